// Round 1
// baseline (243.597 us; speedup 1.0000x reference)
//
#include <hip/hip_runtime.h>
#include <hip/hip_bf16.h>
#include <stdint.h>

typedef unsigned short u16;
typedef short bf16x8 __attribute__((ext_vector_type(8)));
typedef float f32x4 __attribute__((ext_vector_type(4)));
typedef u16 u16x4 __attribute__((ext_vector_type(4)));

#define DIMX  1024
#define NHEAD 16
#define DH    64
#define INNER 1024
#define BATCH 2
#define SEQ   2048
#define MTOT  (BATCH*SEQ)   /* 4096 */
#define EQKV  (3*INNER)     /* 3072 */

#define BM 128
#define BN 128
#define BK 64

__device__ __forceinline__ u16 f2bf(float f) {
  unsigned int x = __float_as_uint(f);
  unsigned int r = (x + 0x7FFFu + ((x >> 16) & 1u)) >> 16;
  return (u16)r;
}

__device__ __forceinline__ void async16(void* lds, const void* g) {
  __builtin_amdgcn_global_load_lds(
      (const __attribute__((address_space(1))) unsigned int*)g,
      (__attribute__((address_space(3))) unsigned int*)lds,
      16, 0, 0);
}

// ---------------- fp32 -> bf16 convert ----------------
__global__ void cvt_kernel(const float* __restrict__ in, u16* __restrict__ out, int n4) {
  int i = blockIdx.x * blockDim.x + threadIdx.x;
  if (i < n4) {
    float4 v = ((const float4*)in)[i];
    u16x4 o;
    o[0] = f2bf(v.x); o[1] = f2bf(v.y); o[2] = f2bf(v.z); o[3] = f2bf(v.w);
    ((u16x4*)out)[i] = o;
  }
}

// ---------------- QKV projection GEMM ----------------
// C[m][e] = sum_k X[m][k] * W[e][k];  scatter to Q (scaled), K, Vt (transposed)
__global__ __launch_bounds__(256) void gemm_qkv(const u16* __restrict__ X, const u16* __restrict__ W,
                                                u16* __restrict__ Qo, u16* __restrict__ Ko,
                                                u16* __restrict__ Vt) {
  __shared__ short sA[BM*BK];
  __shared__ short sB[BN*BK];
  const int tid = threadIdx.x;
  const int wv = tid >> 6, l = tid & 63;
  const int lo = l & 15, hi = l >> 4;
  const int tn = blockIdx.x * BN;
  const int tm = blockIdx.y * BM;
  const int wr = wv >> 1, wc = wv & 1;

  f32x4 acc[4][4];
#pragma unroll
  for (int i = 0; i < 4; i++)
#pragma unroll
    for (int j = 0; j < 4; j++) acc[i][j] = (f32x4){0.f, 0.f, 0.f, 0.f};

  for (int k0 = 0; k0 < DIMX; k0 += BK) {
#pragma unroll
    for (int c = 0; c < 4; c++) {
      int rbase = (c * 4 + wv) * 8;
      async16(&sA[rbase * BK], &X[(size_t)(tm + rbase + (l >> 3)) * DIMX + k0 + (l & 7) * 8]);
      async16(&sB[rbase * BK], &W[(size_t)(tn + rbase + (l >> 3)) * DIMX + k0 + (l & 7) * 8]);
    }
    __syncthreads();
#pragma unroll
    for (int ks = 0; ks < 2; ks++) {
      bf16x8 af[4], bf[4];
#pragma unroll
      for (int i = 0; i < 4; i++) af[i] = *(const bf16x8*)&sA[(wr * 64 + i * 16 + lo) * BK + ks * 32 + hi * 8];
#pragma unroll
      for (int j = 0; j < 4; j++) bf[j] = *(const bf16x8*)&sB[(wc * 64 + j * 16 + lo) * BK + ks * 32 + hi * 8];
#pragma unroll
      for (int i = 0; i < 4; i++)
#pragma unroll
        for (int j = 0; j < 4; j++)
          acc[i][j] = __builtin_amdgcn_mfma_f32_16x16x32_bf16(af[i], bf[j], acc[i][j], 0, 0, 0);
    }
    __syncthreads();
  }

  const float scale = 0.125f;  // 64^-0.5
#pragma unroll
  for (int i = 0; i < 4; i++) {
    int mbase = tm + wr * 64 + i * 16 + hi * 4;
#pragma unroll
    for (int j = 0; j < 4; j++) {
      int e = tn + wc * 64 + j * 16 + lo;
#pragma unroll
      for (int r = 0; r < 4; r++) {
        int mm = mbase + r;
        int b = mm >> 11, n = mm & 2047;
        float v = acc[i][j][r];
        if (e < INNER) {
          int h = e >> 6, d = e & 63;
          Qo[(((size_t)(b * NHEAD + h)) * SEQ + n) * DH + d] = f2bf(v * scale);
        } else if (e < 2 * INNER) {
          int e2 = e - INNER; int h = e2 >> 6, d = e2 & 63;
          Ko[(((size_t)(b * NHEAD + h)) * SEQ + n) * DH + d] = f2bf(v);
        } else {
          int e2 = e - 2 * INNER; int h = e2 >> 6, d = e2 & 63;
          Vt[(((size_t)(b * NHEAD + h)) * DH + d) * SEQ + n] = f2bf(v);
        }
      }
    }
  }
}

// ---------------- flash attention ----------------
// Q,K: [B*H][N][64] bf16 (Q pre-scaled); Vt: [B*H][64][N] bf16; O: [B*N][1024] bf16
__global__ __launch_bounds__(256) void attn_kernel(const u16* __restrict__ Q, const u16* __restrict__ Kd,
                                                   const u16* __restrict__ Vt, u16* __restrict__ O) {
  __shared__ short sK[64 * 64];   // [kv][d]
  __shared__ short sV[64 * 64];   // [d][kv]
  __shared__ short sP[4][32 * 64]; // per-wave [q][kv]
  const int tid = threadIdx.x, wv = tid >> 6, l = tid & 63;
  const int lo = l & 15, hi = l >> 4;
  const int bh = blockIdx.y;
  const int qw = blockIdx.x * 128 + wv * 32;
  const u16* Qb = Q + (size_t)bh * SEQ * DH;
  const u16* Kb = Kd + (size_t)bh * SEQ * DH;
  const u16* Vb = Vt + (size_t)bh * DH * SEQ;

  bf16x8 qf[2][2];
#pragma unroll
  for (int mi = 0; mi < 2; mi++)
#pragma unroll
    for (int kd = 0; kd < 2; kd++)
      qf[mi][kd] = *(const bf16x8*)&Qb[(size_t)(qw + mi * 16 + lo) * DH + kd * 32 + hi * 8];

  f32x4 o[2][4];
  float mrun[2][4], lrun[2][4];
#pragma unroll
  for (int mi = 0; mi < 2; mi++) {
#pragma unroll
    for (int ni = 0; ni < 4; ni++) o[mi][ni] = (f32x4){0.f, 0.f, 0.f, 0.f};
#pragma unroll
    for (int r = 0; r < 4; r++) { mrun[mi][r] = -1e30f; lrun[mi][r] = 0.f; }
  }

  for (int t = 0; t < SEQ / 64; t++) {
    int kv0 = t * 64;
#pragma unroll
    for (int c = 0; c < 2; c++) {
      int rbase = wv * 16 + c * 8;
      async16(&sK[rbase * 64], &Kb[(size_t)(kv0 + rbase + (l >> 3)) * DH + (l & 7) * 8]);
      async16(&sV[rbase * 64], &Vb[(size_t)(rbase + (l >> 3)) * SEQ + kv0 + (l & 7) * 8]);
    }
    __syncthreads();

    // S = Q K^T  (32 q rows x 64 kv cols per wave)
    f32x4 s[2][4];
#pragma unroll
    for (int kb = 0; kb < 4; kb++) {
      bf16x8 kf0 = *(const bf16x8*)&sK[(kb * 16 + lo) * 64 + hi * 8];
      bf16x8 kf1 = *(const bf16x8*)&sK[(kb * 16 + lo) * 64 + 32 + hi * 8];
#pragma unroll
      for (int mi = 0; mi < 2; mi++) {
        f32x4 z = (f32x4){0.f, 0.f, 0.f, 0.f};
        z = __builtin_amdgcn_mfma_f32_16x16x32_bf16(qf[mi][0], kf0, z, 0, 0, 0);
        z = __builtin_amdgcn_mfma_f32_16x16x32_bf16(qf[mi][1], kf1, z, 0, 0, 0);
        s[mi][kb] = z;
      }
    }

    // online softmax (row q = mi*16 + hi*4 + r; its 16 k-values per block live across lanes lo=0..15)
#pragma unroll
    for (int mi = 0; mi < 2; mi++) {
#pragma unroll
      for (int r = 0; r < 4; r++) {
        float mx = fmaxf(fmaxf(s[mi][0][r], s[mi][1][r]), fmaxf(s[mi][2][r], s[mi][3][r]));
        mx = fmaxf(mx, __shfl_xor(mx, 1));
        mx = fmaxf(mx, __shfl_xor(mx, 2));
        mx = fmaxf(mx, __shfl_xor(mx, 4));
        mx = fmaxf(mx, __shfl_xor(mx, 8));
        float mnew = fmaxf(mrun[mi][r], mx);
        float alpha = __expf(mrun[mi][r] - mnew);
        mrun[mi][r] = mnew;
        float rs = 0.f;
#pragma unroll
        for (int kb = 0; kb < 4; kb++) {
          float p = __expf(s[mi][kb][r] - mnew);
          s[mi][kb][r] = p;
          rs += p;
        }
        rs += __shfl_xor(rs, 1);
        rs += __shfl_xor(rs, 2);
        rs += __shfl_xor(rs, 4);
        rs += __shfl_xor(rs, 8);
        lrun[mi][r] = lrun[mi][r] * alpha + rs;
#pragma unroll
        for (int ni = 0; ni < 4; ni++) o[mi][ni][r] *= alpha;
      }
    }

    // P -> LDS (bf16), per-wave buffer; in-wave DS ops are in-order, no barrier needed
    short* pw = &sP[wv][0];
#pragma unroll
    for (int mi = 0; mi < 2; mi++)
#pragma unroll
      for (int kb = 0; kb < 4; kb++)
#pragma unroll
        for (int r = 0; r < 4; r++)
          pw[(mi * 16 + hi * 4 + r) * 64 + kb * 16 + lo] = (short)f2bf(s[mi][kb][r]);

    // O += P V
#pragma unroll
    for (int ks = 0; ks < 2; ks++) {
      bf16x8 pf[2];
#pragma unroll
      for (int mi = 0; mi < 2; mi++) pf[mi] = *(const bf16x8*)&pw[(mi * 16 + lo) * 64 + ks * 32 + hi * 8];
#pragma unroll
      for (int ni = 0; ni < 4; ni++) {
        bf16x8 vf = *(const bf16x8*)&sV[(ni * 16 + lo) * 64 + ks * 32 + hi * 8];
#pragma unroll
        for (int mi = 0; mi < 2; mi++)
          o[mi][ni] = __builtin_amdgcn_mfma_f32_16x16x32_bf16(pf[mi], vf, o[mi][ni], 0, 0, 0);
      }
    }
    __syncthreads();
  }

  int b = bh >> 4, h = bh & 15;
#pragma unroll
  for (int mi = 0; mi < 2; mi++) {
#pragma unroll
    for (int r = 0; r < 4; r++) {
      float inv = 1.0f / lrun[mi][r];
      int n = qw + mi * 16 + hi * 4 + r;
#pragma unroll
      for (int ni = 0; ni < 4; ni++)
        O[((size_t)(b * SEQ + n)) * INNER + h * 64 + ni * 16 + lo] = f2bf(o[mi][ni][r] * inv);
    }
  }
}

// ---------------- output projection GEMM ----------------
// out[m][o] = sum_i A[m][i] * W[o][i] + bias[o]   (fp32 out)
__global__ __launch_bounds__(256) void gemm_out(const u16* __restrict__ A, const u16* __restrict__ W,
                                                const float* __restrict__ bias, float* __restrict__ out) {
  __shared__ short sA[BM*BK];
  __shared__ short sB[BN*BK];
  const int tid = threadIdx.x;
  const int wv = tid >> 6, l = tid & 63;
  const int lo = l & 15, hi = l >> 4;
  const int tn = blockIdx.x * BN;
  const int tm = blockIdx.y * BM;
  const int wr = wv >> 1, wc = wv & 1;

  f32x4 acc[4][4];
#pragma unroll
  for (int i = 0; i < 4; i++)
#pragma unroll
    for (int j = 0; j < 4; j++) acc[i][j] = (f32x4){0.f, 0.f, 0.f, 0.f};

  for (int k0 = 0; k0 < INNER; k0 += BK) {
#pragma unroll
    for (int c = 0; c < 4; c++) {
      int rbase = (c * 4 + wv) * 8;
      async16(&sA[rbase * BK], &A[(size_t)(tm + rbase + (l >> 3)) * INNER + k0 + (l & 7) * 8]);
      async16(&sB[rbase * BK], &W[(size_t)(tn + rbase + (l >> 3)) * INNER + k0 + (l & 7) * 8]);
    }
    __syncthreads();
#pragma unroll
    for (int ks = 0; ks < 2; ks++) {
      bf16x8 af[4], bf[4];
#pragma unroll
      for (int i = 0; i < 4; i++) af[i] = *(const bf16x8*)&sA[(wr * 64 + i * 16 + lo) * BK + ks * 32 + hi * 8];
#pragma unroll
      for (int j = 0; j < 4; j++) bf[j] = *(const bf16x8*)&sB[(wc * 64 + j * 16 + lo) * BK + ks * 32 + hi * 8];
#pragma unroll
      for (int i = 0; i < 4; i++)
#pragma unroll
        for (int j = 0; j < 4; j++)
          acc[i][j] = __builtin_amdgcn_mfma_f32_16x16x32_bf16(af[i], bf[j], acc[i][j], 0, 0, 0);
    }
    __syncthreads();
  }

#pragma unroll
  for (int i = 0; i < 4; i++) {
    int mbase = tm + wr * 64 + i * 16 + hi * 4;
#pragma unroll
    for (int j = 0; j < 4; j++) {
      int col = tn + wc * 64 + j * 16 + lo;
      float bv = bias[col];
#pragma unroll
      for (int r = 0; r < 4; r++)
        out[(size_t)(mbase + r) * DIMX + col] = acc[i][j][r] + bv;
    }
  }
}

extern "C" void kernel_launch(void* const* d_in, const int* in_sizes, int n_in,
                              void* d_out, int out_size, void* d_ws, size_t ws_size,
                              hipStream_t stream) {
  const float* x     = (const float*)d_in[0];
  const float* w_qkv = (const float*)d_in[1];
  const float* w_out = (const float*)d_in[2];
  const float* b_out = (const float*)d_in[3];

  char* ws = (char*)d_ws;
  // byte offsets (all 256-aligned)
  u16* xb    = (u16*)(ws);                         // 4096*1024*2 = 8 MB
  u16* wqkvb = (u16*)(ws + (size_t)8  * (1<<20));  // 6 MB
  u16* woutb = (u16*)(ws + (size_t)14 * (1<<20));  // 2 MB
  u16* Qd    = (u16*)(ws + (size_t)16 * (1<<20));  // 8 MB
  u16* Kdd   = (u16*)(ws + (size_t)24 * (1<<20));  // 8 MB
  u16* Vtd   = (u16*)(ws + (size_t)32 * (1<<20));  // 8 MB
  u16* Od    = (u16*)(ws + (size_t)40 * (1<<20));  // 8 MB  (total 48 MB)

  cvt_kernel<<<(MTOT * DIMX / 4 + 255) / 256, 256, 0, stream>>>(x, xb, MTOT * DIMX / 4);
  cvt_kernel<<<(EQKV * DIMX / 4 + 255) / 256, 256, 0, stream>>>(w_qkv, wqkvb, EQKV * DIMX / 4);
  cvt_kernel<<<(DIMX * INNER / 4 + 255) / 256, 256, 0, stream>>>(w_out, woutb, DIMX * INNER / 4);

  gemm_qkv<<<dim3(EQKV / BN, MTOT / BM), 256, 0, stream>>>(xb, wqkvb, Qd, Kdd, Vtd);
  attn_kernel<<<dim3(SEQ / 128, BATCH * NHEAD), 256, 0, stream>>>(Qd, Kdd, Vtd, Od);
  gemm_out<<<dim3(DIMX / BN, MTOT / BM), 256, 0, stream>>>(Od, woutb, b_out, (float*)d_out);
}